// Round 9
// baseline (1319.505 us; speedup 1.0000x reference)
//
#include <hip/hip_runtime.h>
#include <hip/hip_bf16.h>

#define NVOC 50257
#define DIM 256
#define HID 256
#define NLAYER 2
#define SEQ 128
#define BATCH 16
#define GUARD (1 << 20)
#define NCHUNK 197                   // ceil(NVOC/256)
#define DECBLKS (32 * NCHUNK)

typedef __bf16 bf16x8 __attribute__((ext_vector_type(8)));
typedef float f32x4 __attribute__((ext_vector_type(4)));
typedef unsigned short u16;
typedef unsigned int u32;
typedef unsigned long long u64;

#define AL64(p)   __hip_atomic_load((const u64*)(p), __ATOMIC_RELAXED, __HIP_MEMORY_SCOPE_AGENT)
#define AS32(p,v) __hip_atomic_store((u32*)(p), (v), __ATOMIC_RELAXED, __HIP_MEMORY_SCOPE_AGENT)

__device__ __forceinline__ float fsig(float z) { return 1.f / (1.f + __expf(-z)); }
__device__ __forceinline__ float ftanh(float z) {
  const float x = fminf(fmaxf(z, -15.f), 15.f);
  const float e = __expf(2.f * x);
  return (e - 1.f) / (e + 1.f);
}
__device__ __forceinline__ bf16x8 cvt8(const float4 u0, const float4 u1) {
  bf16x8 v;
  v[0] = (__bf16)u0.x; v[1] = (__bf16)u0.y; v[2] = (__bf16)u0.z; v[3] = (__bf16)u0.w;
  v[4] = (__bf16)u1.x; v[5] = (__bf16)u1.y; v[6] = (__bf16)u1.z; v[7] = (__bf16)u1.w;
  return v;
}

// ---------------- flag zero (runs before mega each call: replay/poison-safe) ----------------
__global__ void zero_kernel(u32* __restrict__ flg) {
  for (int i = threadIdx.x; i < SEQ * 8; i += 256) AS32(&flg[i], 0u);
}

// ---------------- XU precompute (layer-0 bias folded in) ----------------
// XU[t*16+b][g*256+c] = emb[tok[t,b]] @ U_g + b_g. Grid (128,4) x 256 thr.
__global__ __launch_bounds__(256) void xu_kernel(
    const int* __restrict__ tokp, const float* __restrict__ embp,
    const float* __restrict__ uF, const float* __restrict__ uI,
    const float* __restrict__ uC, const float* __restrict__ uO,
    const float* __restrict__ bF, const float* __restrict__ bI,
    const float* __restrict__ bC, const float* __restrict__ bO,
    float* __restrict__ XU)
{
  const int tid = threadIdx.x;
  const int lane = tid & 63, wv = tid >> 6, r16 = lane & 15, kgrp = lane >> 4;
  const int m0 = blockIdx.x * 16;
  const int n0 = blockIdx.y * 256 + wv * 64;
  const float* Ug[4] = {uF, uI, uC, uO};
  const float* Bp[4] = {bF, bI, bC, bO};

  bf16x8 b[4][8];
  float bias[4];
#pragma unroll
  for (int nt = 0; nt < 4; ++nt) {
    const int n = n0 + nt * 16 + r16;
    const float* U = Ug[n >> 8];
    const int c = n & 255;
    bias[nt] = Bp[n >> 8][c];
#pragma unroll
    for (int kk = 0; kk < 8; ++kk) {
      const int kb = kk * 32 + kgrp * 8;
      bf16x8 v;
#pragma unroll
      for (int e = 0; e < 8; ++e) v[e] = (__bf16)U[(size_t)(kb + e) * HID + c];
      b[nt][kk] = v;
    }
  }

  const int tok = tokp[m0 + r16];
  const float* x = embp + (size_t)tok * DIM;
  bf16x8 a[8];
#pragma unroll
  for (int kk = 0; kk < 8; ++kk) {
    const int kb = kk * 32 + kgrp * 8;
    a[kk] = cvt8(*reinterpret_cast<const float4*>(x + kb),
                 *reinterpret_cast<const float4*>(x + kb + 4));
  }
#pragma unroll
  for (int nt = 0; nt < 4; ++nt) {
    f32x4 acc = {0.f, 0.f, 0.f, 0.f};
#pragma unroll
    for (int kk = 0; kk < 8; ++kk)
      acc = __builtin_amdgcn_mfma_f32_16x16x32_bf16(a[kk], b[nt][kk], acc, 0, 0, 0);
    const int n = n0 + nt * 16 + r16;
#pragma unroll
    for (int r = 0; r < 4; ++r)
      XU[(size_t)(m0 + kgrp * 4 + r) * 1024 + n] = acc[r] + bias[nt];
  }
}

// ---------------- mega kernel: LSTM (bx 0..7) + fused decoder (bx 8..) ----------------
// LSTM: R8-proven structure. bx 0..3: L0 slice jj (cols [64jj,+64)), K=256.
//       bx 4..7: L1 slice jj, K=512. Wave: 16-col tile x gate pair. Sync: tid0-only
//       flag poll (no fence) -> barrier -> plain b128 h loads -> MFMA -> LDS gate
//       combine -> packed-bf16 write-through publish -> barrier -> tid0 flag store.
// DEC:  block db=bx-8: m-chunk mb=db%32 (rows [64mb,+64) = t 4mb..4mb+3),
//       n-chunk nb=db/32 (vocab cols [256nb,+256), 8 waves x 32 cols).
//       Prefetch dec_w f32 -> bf16 frags (in-register convert; prep kernel deleted),
//       then tid0 polls the 4 L1 flags at t=4mb+3 (monotonic per-WG => covers all 4 t)
//       with s_sleep backoff, then plain h1 loads + MFMA + logits store.
//       Dec never blocks LSTM; LSTM never waits on dec => deadlock-free.
__global__ __launch_bounds__(512, 2) void mega_kernel(
    const float* __restrict__ wF, const float* __restrict__ wI,
    const float* __restrict__ wC, const float* __restrict__ wO,
    const float* __restrict__ uF, const float* __restrict__ uI,
    const float* __restrict__ uC, const float* __restrict__ uO,
    const float* __restrict__ bF, const float* __restrict__ bI,
    const float* __restrict__ bC, const float* __restrict__ bO,
    const float* __restrict__ XU, u32* __restrict__ h0w, u32* __restrict__ h1w,
    u32* __restrict__ flg, const float* __restrict__ dw,
    const float* __restrict__ dbp, float* __restrict__ dout)
{
  const int tid  = threadIdx.x;
  const int lane = tid & 63;
  const int wv   = tid >> 6;        // 0..7
  const int r16  = lane & 15;
  const int kgrp = lane >> 4;
  const int bx   = blockIdx.x;

  __shared__ float gbuf[4][16][72];

  if (bx >= 8) {
    // ================= decoder block =================
    const int db = bx - 8;
    const int mb = db & 31;          // m-chunk: rows [mb*64, +64)
    const int nb = db >> 5;          // vocab chunk: cols [nb*256, +256)
    const int n0 = nb * 256 + wv * 32;

    // ---- prefetch B: dec_w f32 -> bf16 frags (overlaps the wait) ----
    bf16x8 b[2][8];
    float bb[2];
#pragma unroll
    for (int nt = 0; nt < 2; ++nt) {
      const int v = n0 + nt * 16 + r16;
      const int vc = (v < NVOC) ? v : (NVOC - 1);
      bb[nt] = dbp[vc];
      const float* bp = dw + (size_t)vc * HID + kgrp * 8;
#pragma unroll
      for (int kk = 0; kk < 8; ++kk)
        b[nt][kk] = cvt8(*reinterpret_cast<const float4*>(bp + kk * 32),
                         *reinterpret_cast<const float4*>(bp + kk * 32 + 4));
    }

    // ---- wait for h1 rows: L1 flags at t = 4mb+3 (monotonic per jj) ----
    if (tid == 0) {
      const int tl = mb * 4 + 3;
      int gd = 0;
      for (;;) {
        const u64 f0 = AL64(flg + (size_t)tl * 8 + 4);
        const u64 f1 = AL64(flg + (size_t)tl * 8 + 6);
        if (((u32)f0 & (u32)(f0 >> 32) & (u32)f1 & (u32)(f1 >> 32)) != 0u) break;
        if (++gd >= GUARD) break;
        __builtin_amdgcn_s_sleep(32);
      }
    }
    __syncthreads();

    // ---- A: h1 rows (plain b128, flag-gated) ----
    const u16* htb = (const u16*)h1w;
    bf16x8 a[4][8];
#pragma unroll
    for (int mt = 0; mt < 4; ++mt) {
      const u16* ap = htb + ((size_t)(mb * 64 + mt * 16 + r16)) * HID + kgrp * 8;
#pragma unroll
      for (int kk = 0; kk < 8; ++kk)
        a[mt][kk] = *reinterpret_cast<const bf16x8*>(ap + kk * 32);
    }

    f32x4 acc[4][2];
#pragma unroll
    for (int mt = 0; mt < 4; ++mt)
#pragma unroll
      for (int nt = 0; nt < 2; ++nt) {
        acc[mt][nt][0] = 0.f; acc[mt][nt][1] = 0.f;
        acc[mt][nt][2] = 0.f; acc[mt][nt][3] = 0.f;
      }
#pragma unroll
    for (int kk = 0; kk < 8; ++kk)
#pragma unroll
      for (int nt = 0; nt < 2; ++nt) {
        const bf16x8 bv = b[nt][kk];
#pragma unroll
        for (int mt = 0; mt < 4; ++mt)
          acc[mt][nt] = __builtin_amdgcn_mfma_f32_16x16x32_bf16(a[mt][kk], bv, acc[mt][nt], 0, 0, 0);
      }

#pragma unroll
    for (int nt = 0; nt < 2; ++nt) {
      const int v = n0 + nt * 16 + r16;
      if (v < NVOC) {
#pragma unroll
        for (int mt = 0; mt < 4; ++mt)
#pragma unroll
          for (int r = 0; r < 4; ++r)
            dout[(size_t)(mb * 64 + mt * 16 + kgrp * 4 + r) * NVOC + v] = acc[mt][nt][r] + bb[nt];
      }
    }
    return;
  }

  // ================= LSTM blocks (R8-proven) =================
  const int colt = wv & 3;
  const int gp   = wv >> 2;
  const int l    = bx >> 2;
  const int jj   = bx & 3;
  const int n    = jj * 64 + colt * 16 + r16;
  const int g0   = gp * 2;

  const float* Wg[4] = {wF, wI, wC, wO};
  const float* Ug[4] = {uF, uI, uC, uO};
  const float* Bg[4] = {bF, bI, bC, bO};
  const u16* h0s = (const u16*)h0w;
  const u16* h1s = (const u16*)h1w;
  const size_t logitsN = (size_t)SEQ * BATCH * NVOC;

  bf16x8 wa[2][8];
  bf16x8 wb[2][8];
  float bias[2];
#pragma unroll
  for (int gi = 0; gi < 2; ++gi) {
    const int g = g0 + gi;
    bias[gi] = Bg[g][n];
#pragma unroll
    for (int kk = 0; kk < 8; ++kk) {
      const int kb = kk * 32 + kgrp * 8;
      bf16x8 v;
#pragma unroll
      for (int e = 0; e < 8; ++e) v[e] = (__bf16)Wg[g][(size_t)(kb + e) * HID + n];
      wa[gi][kk] = v;
      if (l == 1) {
        bf16x8 u;
#pragma unroll
        for (int e = 0; e < 8; ++e) u[e] = (__bf16)Ug[g][(size_t)(kb + e) * HID + n];
        wb[gi][kk] = u;
      }
    }
  }

  const int eb = tid >> 5;
  const int ec = (tid & 31) * 2;
  float c0 = 0.f, c1 = 0.f;

  for (int t = 0; t < SEQ; ++t) {
    if (tid == 0) {
      int gd = 0;
      if (l == 0) {
        if (t > 0)
          for (;;) {
            const u64 f0 = AL64(flg + (size_t)(t - 1) * 8);
            const u64 f1 = AL64(flg + (size_t)(t - 1) * 8 + 2);
            if (((u32)f0 & (u32)(f0 >> 32) & (u32)f1 & (u32)(f1 >> 32)) != 0u) break;
            if (++gd >= GUARD) break;
          }
      } else {
        for (;;) {
          const u64 f0 = AL64(flg + (size_t)t * 8);
          const u64 f1 = AL64(flg + (size_t)t * 8 + 2);
          u32 ok = (u32)f0 & (u32)(f0 >> 32) & (u32)f1 & (u32)(f1 >> 32);
          if (t > 0) {
            const u64 g1 = AL64(flg + (size_t)(t - 1) * 8 + 4);
            const u64 g2 = AL64(flg + (size_t)(t - 1) * 8 + 6);
            ok &= (u32)g1 & (u32)(g1 >> 32) & (u32)g2 & (u32)(g2 >> 32);
          }
          if (ok) break;
          if (++gd >= GUARD) break;
        }
      }
    }
    __syncthreads();

    bf16x8 hA[8], hB[8];
    if (l == 0) {
      if (t > 0) {
        const u16* hp = h0s + ((size_t)(t - 1) * BATCH + r16) * HID + kgrp * 8;
#pragma unroll
        for (int kk = 0; kk < 8; ++kk)
          hA[kk] = *reinterpret_cast<const bf16x8*>(hp + kk * 32);
      }
    } else {
      const u16* xp = h0s + ((size_t)t * BATCH + r16) * HID + kgrp * 8;
#pragma unroll
      for (int kk = 0; kk < 8; ++kk)
        hA[kk] = *reinterpret_cast<const bf16x8*>(xp + kk * 32);
      if (t > 0) {
        const u16* hp = h1s + ((size_t)(t - 1) * BATCH + r16) * HID + kgrp * 8;
#pragma unroll
        for (int kk = 0; kk < 8; ++kk)
          hB[kk] = *reinterpret_cast<const bf16x8*>(hp + kk * 32);
      }
    }

    f32x4 acc[2];
#pragma unroll
    for (int gi = 0; gi < 2; ++gi) { acc[gi][0]=0.f; acc[gi][1]=0.f; acc[gi][2]=0.f; acc[gi][3]=0.f; }
    if (l == 0) {
      if (t > 0) {
#pragma unroll
        for (int kk = 0; kk < 8; ++kk)
#pragma unroll
          for (int gi = 0; gi < 2; ++gi)
            acc[gi] = __builtin_amdgcn_mfma_f32_16x16x32_bf16(hA[kk], wa[gi][kk], acc[gi], 0, 0, 0);
      }
    } else {
#pragma unroll
      for (int kk = 0; kk < 8; ++kk)
#pragma unroll
        for (int gi = 0; gi < 2; ++gi)
          acc[gi] = __builtin_amdgcn_mfma_f32_16x16x32_bf16(hA[kk], wb[gi][kk], acc[gi], 0, 0, 0);
      if (t > 0) {
#pragma unroll
        for (int kk = 0; kk < 8; ++kk)
#pragma unroll
          for (int gi = 0; gi < 2; ++gi)
            acc[gi] = __builtin_amdgcn_mfma_f32_16x16x32_bf16(hB[kk], wa[gi][kk], acc[gi], 0, 0, 0);
      }
    }

#pragma unroll
    for (int gi = 0; gi < 2; ++gi) {
      const int g = g0 + gi;
#pragma unroll
      for (int r = 0; r < 4; ++r) {
        float z;
        if (l == 0)
          z = acc[gi][r] + XU[(size_t)(t * 16 + kgrp * 4 + r) * 1024 + g * 256 + n];
        else
          z = acc[gi][r] + bias[gi];
        gbuf[g][kgrp * 4 + r][colt * 16 + r16] = (g == 2) ? ftanh(z) : fsig(z);
      }
    }
    __syncthreads();

    const float ff0 = gbuf[0][eb][ec], ff1 = gbuf[0][eb][ec + 1];
    const float ii0 = gbuf[1][eb][ec], ii1 = gbuf[1][eb][ec + 1];
    const float gg0 = gbuf[2][eb][ec], gg1 = gbuf[2][eb][ec + 1];
    const float oo0 = gbuf[3][eb][ec], oo1 = gbuf[3][eb][ec + 1];
    c0 = ff0 * c0 + ii0 * gg0;
    c1 = ff1 * c1 + ii1 * gg1;
    const float hv0 = oo0 * ftanh(c0);
    const float hv1 = oo1 * ftanh(c1);
    const u32 pk = (u32)__builtin_bit_cast(u16, (__bf16)hv0) |
                   ((u32)__builtin_bit_cast(u16, (__bf16)hv1) << 16);
    u32* hw = l ? h1w : h0w;
    AS32(hw + ((size_t)t * BATCH + eb) * 128 + jj * 32 + (ec >> 1), pk);

    if (t == SEQ - 1) {
      const int nn = jj * 64 + ec;
      float* hT = dout + logitsN + ((size_t)l * BATCH + eb) * HID + nn;
      float* cT = dout + logitsN + (size_t)NLAYER * BATCH * HID + ((size_t)l * BATCH + eb) * HID + nn;
      hT[0] = hv0; hT[1] = hv1;
      cT[0] = c0;  cT[1] = c1;
    }
    __syncthreads();                // vmcnt(0) drain: publishes complete before flag
    if (tid == 0) AS32(&flg[(size_t)t * 8 + l * 4 + jj], 1u);
  }
}

extern "C" void kernel_launch(void* const* d_in, const int* in_sizes, int n_in,
                              void* d_out, int out_size, void* d_ws, size_t ws_size,
                              hipStream_t stream) {
  const int*   tokp = (const int*)d_in[0];
  const float* embp = (const float*)d_in[1];
  const float* wF = (const float*)d_in[2];
  const float* uF = (const float*)d_in[3];
  const float* bF = (const float*)d_in[4];
  const float* wI = (const float*)d_in[5];
  const float* uI = (const float*)d_in[6];
  const float* bI = (const float*)d_in[7];
  const float* wC = (const float*)d_in[8];
  const float* uC = (const float*)d_in[9];
  const float* bC = (const float*)d_in[10];
  const float* wO = (const float*)d_in[11];
  const float* uO = (const float*)d_in[12];
  const float* bO = (const float*)d_in[13];
  const float* dw = (const float*)d_in[14];
  const float* db = (const float*)d_in[15];
  float* out = (float*)d_out;

  char* ws = (char*)d_ws;
  size_t off = 0;
  float* XU = (float*)(ws + off); off += (size_t)SEQ * BATCH * 1024 * 4;   // 8 MB
  u32* h0w = (u32*)(ws + off); off += (size_t)SEQ * BATCH * HID * 2;       // bf16 h0
  u32* h1w = (u32*)(ws + off); off += (size_t)SEQ * BATCH * HID * 2;       // bf16 h1
  u32* flg = (u32*)(ws + off); off += (size_t)SEQ * 8 * 4;

  // zero (flags, replay-safe) -> xu (XU with L0 bias folded) ->
  // mega: LSTM blocks 0..7 + 6304 decoder blocks consuming h1 as produced.
  zero_kernel<<<1, 256, 0, stream>>>(flg);
  xu_kernel<<<dim3(128, 4), 256, 0, stream>>>(tokp, embp, uF, uI, uC, uO,
                                              bF, bI, bC, bO, XU);
  mega_kernel<<<8 + DECBLKS, 512, 0, stream>>>(wF, wI, wC, wO, uF, uI, uC, uO,
                                               bF, bI, bC, bO, XU, h0w, h1w, flg,
                                               dw, db, out);
}

// Round 10
// 856.954 us; speedup vs baseline: 1.5398x; 1.5398x over previous
//
#include <hip/hip_runtime.h>
#include <hip/hip_bf16.h>

#define NVOC 50257
#define DIM 256
#define HID 256
#define NLAYER 2
#define SEQ 128
#define BATCH 16
#define GUARD (1 << 20)
#define NCHUNK 197                   // ceil(NVOC/256)
#define DECBLKS (32 * NCHUNK)

typedef __bf16 bf16x8 __attribute__((ext_vector_type(8)));
typedef float f32x4 __attribute__((ext_vector_type(4)));
typedef unsigned short u16;
typedef unsigned int u32;
typedef unsigned long long u64;

#define AL64(p)   __hip_atomic_load((const u64*)(p), __ATOMIC_RELAXED, __HIP_MEMORY_SCOPE_AGENT)
#define AS32(p,v) __hip_atomic_store((u32*)(p), (v), __ATOMIC_RELAXED, __HIP_MEMORY_SCOPE_AGENT)

__device__ __forceinline__ float fsig(float z) { return 1.f / (1.f + __expf(-z)); }
__device__ __forceinline__ float ftanh(float z) {
  const float x = fminf(fmaxf(z, -15.f), 15.f);
  const float e = __expf(2.f * x);
  return (e - 1.f) / (e + 1.f);
}
__device__ __forceinline__ bf16x8 cvt8(const float4 u0, const float4 u1) {
  bf16x8 v;
  v[0] = (__bf16)u0.x; v[1] = (__bf16)u0.y; v[2] = (__bf16)u0.z; v[3] = (__bf16)u0.w;
  v[4] = (__bf16)u1.x; v[5] = (__bf16)u1.y; v[6] = (__bf16)u1.z; v[7] = (__bf16)u1.w;
  return v;
}

// ---------------- flag zero (runs before mega each call: replay/poison-safe) ----------------
__global__ void zero_kernel(u32* __restrict__ flg) {
  for (int i = threadIdx.x; i < SEQ * 8; i += 256) AS32(&flg[i], 0u);
}

// ---------------- XU precompute (layer-0 bias folded in) ----------------
// XU[t*16+b][g*256+c] = emb[tok[t,b]] @ U_g + b_g. Grid (128,4) x 256 thr.
__global__ __launch_bounds__(256) void xu_kernel(
    const int* __restrict__ tokp, const float* __restrict__ embp,
    const float* __restrict__ uF, const float* __restrict__ uI,
    const float* __restrict__ uC, const float* __restrict__ uO,
    const float* __restrict__ bF, const float* __restrict__ bI,
    const float* __restrict__ bC, const float* __restrict__ bO,
    float* __restrict__ XU)
{
  const int tid = threadIdx.x;
  const int lane = tid & 63, wv = tid >> 6, r16 = lane & 15, kgrp = lane >> 4;
  const int m0 = blockIdx.x * 16;
  const int n0 = blockIdx.y * 256 + wv * 64;
  const float* Ug[4] = {uF, uI, uC, uO};
  const float* Bp[4] = {bF, bI, bC, bO};

  bf16x8 b[4][8];
  float bias[4];
#pragma unroll
  for (int nt = 0; nt < 4; ++nt) {
    const int n = n0 + nt * 16 + r16;
    const float* U = Ug[n >> 8];
    const int c = n & 255;
    bias[nt] = Bp[n >> 8][c];
#pragma unroll
    for (int kk = 0; kk < 8; ++kk) {
      const int kb = kk * 32 + kgrp * 8;
      bf16x8 v;
#pragma unroll
      for (int e = 0; e < 8; ++e) v[e] = (__bf16)U[(size_t)(kb + e) * HID + c];
      b[nt][kk] = v;
    }
  }

  const int tok = tokp[m0 + r16];
  const float* x = embp + (size_t)tok * DIM;
  bf16x8 a[8];
#pragma unroll
  for (int kk = 0; kk < 8; ++kk) {
    const int kb = kk * 32 + kgrp * 8;
    a[kk] = cvt8(*reinterpret_cast<const float4*>(x + kb),
                 *reinterpret_cast<const float4*>(x + kb + 4));
  }
#pragma unroll
  for (int nt = 0; nt < 4; ++nt) {
    f32x4 acc = {0.f, 0.f, 0.f, 0.f};
#pragma unroll
    for (int kk = 0; kk < 8; ++kk)
      acc = __builtin_amdgcn_mfma_f32_16x16x32_bf16(a[kk], b[nt][kk], acc, 0, 0, 0);
    const int n = n0 + nt * 16 + r16;
#pragma unroll
    for (int r = 0; r < 4; ++r)
      XU[(size_t)(m0 + kgrp * 4 + r) * 1024 + n] = acc[r] + bias[nt];
  }
}

// ---------------- mega kernel: LSTM (bx 0..7) + fused decoder (bx 8..) ----------------
// LSTM: R8 structure + XU-hoist (L0) + split-wait (L1).
// DEC:  mb-MAJOR ordering (db/NCHUNK = m-chunk): resident dec blocks track LSTM
//       progress temporally; s_sleep(64) backoff keeps poll traffic negligible.
//       Dec never blocks LSTM; LSTM never waits on dec => deadlock-free.
__global__ __launch_bounds__(512, 2) void mega_kernel(
    const float* __restrict__ wF, const float* __restrict__ wI,
    const float* __restrict__ wC, const float* __restrict__ wO,
    const float* __restrict__ uF, const float* __restrict__ uI,
    const float* __restrict__ uC, const float* __restrict__ uO,
    const float* __restrict__ bF, const float* __restrict__ bI,
    const float* __restrict__ bC, const float* __restrict__ bO,
    const float* __restrict__ XU, u32* __restrict__ h0w, u32* __restrict__ h1w,
    u32* __restrict__ flg, const float* __restrict__ dw,
    const float* __restrict__ dbp, float* __restrict__ dout)
{
  const int tid  = threadIdx.x;
  const int lane = tid & 63;
  const int wv   = tid >> 6;        // 0..7
  const int r16  = lane & 15;
  const int kgrp = lane >> 4;
  const int bx   = blockIdx.x;

  __shared__ float gbuf[4][16][72];

  if (bx >= 8) {
    // ================= decoder block (mb-major) =================
    const int db = bx - 8;
    const int mb = db / NCHUNK;      // m-chunk: rows [mb*64, +64) = t 4mb..4mb+3
    const int nb = db - mb * NCHUNK; // vocab chunk: cols [nb*256, +256)
    const int n0 = nb * 256 + wv * 32;

    // ---- prefetch B: dec_w f32 -> bf16 frags (overlaps the wait) ----
    bf16x8 b[2][8];
    float bb[2];
#pragma unroll
    for (int nt = 0; nt < 2; ++nt) {
      const int v = n0 + nt * 16 + r16;
      const int vc = (v < NVOC) ? v : (NVOC - 1);
      bb[nt] = dbp[vc];
      const float* bp = dw + (size_t)vc * HID + kgrp * 8;
#pragma unroll
      for (int kk = 0; kk < 8; ++kk)
        b[nt][kk] = cvt8(*reinterpret_cast<const float4*>(bp + kk * 32),
                         *reinterpret_cast<const float4*>(bp + kk * 32 + 4));
    }

    // ---- wait for h1 rows: L1 flags at t = 4mb+3 (monotonic per jj) ----
    if (tid == 0) {
      const int tl = mb * 4 + 3;
      int gd = 0;
      for (;;) {
        const u64 f0 = AL64(flg + (size_t)tl * 8 + 4);
        const u64 f1 = AL64(flg + (size_t)tl * 8 + 6);
        if (((u32)f0 & (u32)(f0 >> 32) & (u32)f1 & (u32)(f1 >> 32)) != 0u) break;
        if (++gd >= GUARD) break;
        __builtin_amdgcn_s_sleep(64);
      }
    }
    __syncthreads();

    // ---- A: h1 rows (plain b128, flag-gated) ----
    const u16* htb = (const u16*)h1w;
    bf16x8 a[4][8];
#pragma unroll
    for (int mt = 0; mt < 4; ++mt) {
      const u16* ap = htb + ((size_t)(mb * 64 + mt * 16 + r16)) * HID + kgrp * 8;
#pragma unroll
      for (int kk = 0; kk < 8; ++kk)
        a[mt][kk] = *reinterpret_cast<const bf16x8*>(ap + kk * 32);
    }

    f32x4 acc[4][2];
#pragma unroll
    for (int mt = 0; mt < 4; ++mt)
#pragma unroll
      for (int nt = 0; nt < 2; ++nt) {
        acc[mt][nt][0] = 0.f; acc[mt][nt][1] = 0.f;
        acc[mt][nt][2] = 0.f; acc[mt][nt][3] = 0.f;
      }
#pragma unroll
    for (int kk = 0; kk < 8; ++kk)
#pragma unroll
      for (int nt = 0; nt < 2; ++nt) {
        const bf16x8 bv = b[nt][kk];
#pragma unroll
        for (int mt = 0; mt < 4; ++mt)
          acc[mt][nt] = __builtin_amdgcn_mfma_f32_16x16x32_bf16(a[mt][kk], bv, acc[mt][nt], 0, 0, 0);
      }

#pragma unroll
    for (int nt = 0; nt < 2; ++nt) {
      const int v = n0 + nt * 16 + r16;
      if (v < NVOC) {
#pragma unroll
        for (int mt = 0; mt < 4; ++mt)
#pragma unroll
          for (int r = 0; r < 4; ++r)
            dout[(size_t)(mb * 64 + mt * 16 + kgrp * 4 + r) * NVOC + v] = acc[mt][nt][r] + bb[nt];
      }
    }
    return;
  }

  // ================= LSTM blocks =================
  const int colt = wv & 3;
  const int gp   = wv >> 2;
  const int l    = bx >> 2;
  const int jj   = bx & 3;
  const int n    = jj * 64 + colt * 16 + r16;
  const int g0   = gp * 2;

  const float* Wg[4] = {wF, wI, wC, wO};
  const float* Ug[4] = {uF, uI, uC, uO};
  const float* Bg[4] = {bF, bI, bC, bO};
  const u16* h0s = (const u16*)h0w;
  const u16* h1s = (const u16*)h1w;
  const size_t logitsN = (size_t)SEQ * BATCH * NVOC;

  bf16x8 wa[2][8];
  bf16x8 wb[2][8];
  float bias[2];
#pragma unroll
  for (int gi = 0; gi < 2; ++gi) {
    const int g = g0 + gi;
    bias[gi] = Bg[g][n];
#pragma unroll
    for (int kk = 0; kk < 8; ++kk) {
      const int kb = kk * 32 + kgrp * 8;
      bf16x8 v;
#pragma unroll
      for (int e = 0; e < 8; ++e) v[e] = (__bf16)Wg[g][(size_t)(kb + e) * HID + n];
      wa[gi][kk] = v;
      if (l == 1) {
        bf16x8 u;
#pragma unroll
        for (int e = 0; e < 8; ++e) u[e] = (__bf16)Ug[g][(size_t)(kb + e) * HID + n];
        wb[gi][kk] = u;
      }
    }
  }

  const int eb = tid >> 5;
  const int ec = (tid & 31) * 2;
  float c0 = 0.f, c1 = 0.f;

  for (int t = 0; t < SEQ; ++t) {
    f32x4 acc[2];
#pragma unroll
    for (int gi = 0; gi < 2; ++gi) { acc[gi][0]=0.f; acc[gi][1]=0.f; acc[gi][2]=0.f; acc[gi][3]=0.f; }

    float xuv[2][4];
    if (l == 0) {
      // ---- XU hoist: no flag dependency; latency hides under the poll ----
#pragma unroll
      for (int gi = 0; gi < 2; ++gi)
#pragma unroll
        for (int r = 0; r < 4; ++r)
          xuv[gi][r] = XU[(size_t)(t * 16 + kgrp * 4 + r) * 1024 + (g0 + gi) * 256 + n];

      if (t > 0) {
        if (tid == 0) {
          int gd = 0;
          for (;;) {
            const u64 f0 = AL64(flg + (size_t)(t - 1) * 8);
            const u64 f1 = AL64(flg + (size_t)(t - 1) * 8 + 2);
            if (((u32)f0 & (u32)(f0 >> 32) & (u32)f1 & (u32)(f1 >> 32)) != 0u) break;
            if (++gd >= GUARD) break;
          }
        }
        __syncthreads();
        const u16* hp = h0s + ((size_t)(t - 1) * BATCH + r16) * HID + kgrp * 8;
        bf16x8 hA[8];
#pragma unroll
        for (int kk = 0; kk < 8; ++kk)
          hA[kk] = *reinterpret_cast<const bf16x8*>(hp + kk * 32);
#pragma unroll
        for (int kk = 0; kk < 8; ++kk)
#pragma unroll
          for (int gi = 0; gi < 2; ++gi)
            acc[gi] = __builtin_amdgcn_mfma_f32_16x16x32_bf16(hA[kk], wa[gi][kk], acc[gi], 0, 0, 0);
      }
    } else {
      // ---- split wait 1: own layer flags @ t-1 -> W-part MFMAs ----
      if (t > 0) {
        if (tid == 0) {
          int gd = 0;
          for (;;) {
            const u64 g1 = AL64(flg + (size_t)(t - 1) * 8 + 4);
            const u64 g2 = AL64(flg + (size_t)(t - 1) * 8 + 6);
            if (((u32)g1 & (u32)(g1 >> 32) & (u32)g2 & (u32)(g2 >> 32)) != 0u) break;
            if (++gd >= GUARD) break;
          }
        }
        __syncthreads();
        const u16* hp = h1s + ((size_t)(t - 1) * BATCH + r16) * HID + kgrp * 8;
        bf16x8 hB[8];
#pragma unroll
        for (int kk = 0; kk < 8; ++kk)
          hB[kk] = *reinterpret_cast<const bf16x8*>(hp + kk * 32);
#pragma unroll
        for (int kk = 0; kk < 8; ++kk)
#pragma unroll
          for (int gi = 0; gi < 2; ++gi)
            acc[gi] = __builtin_amdgcn_mfma_f32_16x16x32_bf16(hB[kk], wa[gi][kk], acc[gi], 0, 0, 0);
      }
      // ---- split wait 2: L0 flags @ t -> U-part MFMAs ----
      if (tid == 0) {
        int gd = 0;
        for (;;) {
          const u64 f0 = AL64(flg + (size_t)t * 8);
          const u64 f1 = AL64(flg + (size_t)t * 8 + 2);
          if (((u32)f0 & (u32)(f0 >> 32) & (u32)f1 & (u32)(f1 >> 32)) != 0u) break;
          if (++gd >= GUARD) break;
        }
      }
      __syncthreads();
      const u16* xp = h0s + ((size_t)t * BATCH + r16) * HID + kgrp * 8;
      bf16x8 hA[8];
#pragma unroll
      for (int kk = 0; kk < 8; ++kk)
        hA[kk] = *reinterpret_cast<const bf16x8*>(xp + kk * 32);
#pragma unroll
      for (int kk = 0; kk < 8; ++kk)
#pragma unroll
        for (int gi = 0; gi < 2; ++gi)
          acc[gi] = __builtin_amdgcn_mfma_f32_16x16x32_bf16(hA[kk], wb[gi][kk], acc[gi], 0, 0, 0);
    }

    // ---- activations -> LDS ----
#pragma unroll
    for (int gi = 0; gi < 2; ++gi) {
      const int g = g0 + gi;
#pragma unroll
      for (int r = 0; r < 4; ++r) {
        const float z = acc[gi][r] + ((l == 0) ? xuv[gi][r] : bias[gi]);
        gbuf[g][kgrp * 4 + r][colt * 16 + r16] = (g == 2) ? ftanh(z) : fsig(z);
      }
    }
    __syncthreads();

    const float ff0 = gbuf[0][eb][ec], ff1 = gbuf[0][eb][ec + 1];
    const float ii0 = gbuf[1][eb][ec], ii1 = gbuf[1][eb][ec + 1];
    const float gg0 = gbuf[2][eb][ec], gg1 = gbuf[2][eb][ec + 1];
    const float oo0 = gbuf[3][eb][ec], oo1 = gbuf[3][eb][ec + 1];
    c0 = ff0 * c0 + ii0 * gg0;
    c1 = ff1 * c1 + ii1 * gg1;
    const float hv0 = oo0 * ftanh(c0);
    const float hv1 = oo1 * ftanh(c1);
    const u32 pk = (u32)__builtin_bit_cast(u16, (__bf16)hv0) |
                   ((u32)__builtin_bit_cast(u16, (__bf16)hv1) << 16);
    u32* hw = l ? h1w : h0w;
    AS32(hw + ((size_t)t * BATCH + eb) * 128 + jj * 32 + (ec >> 1), pk);

    if (t == SEQ - 1) {
      const int nn = jj * 64 + ec;
      float* hT = dout + logitsN + ((size_t)l * BATCH + eb) * HID + nn;
      float* cT = dout + logitsN + (size_t)NLAYER * BATCH * HID + ((size_t)l * BATCH + eb) * HID + nn;
      hT[0] = hv0; hT[1] = hv1;
      cT[0] = c0;  cT[1] = c1;
    }
    __syncthreads();                // vmcnt(0) drain: publishes complete before flag
    if (tid == 0) AS32(&flg[(size_t)t * 8 + l * 4 + jj], 1u);
  }
}

extern "C" void kernel_launch(void* const* d_in, const int* in_sizes, int n_in,
                              void* d_out, int out_size, void* d_ws, size_t ws_size,
                              hipStream_t stream) {
  const int*   tokp = (const int*)d_in[0];
  const float* embp = (const float*)d_in[1];
  const float* wF = (const float*)d_in[2];
  const float* uF = (const float*)d_in[3];
  const float* bF = (const float*)d_in[4];
  const float* wI = (const float*)d_in[5];
  const float* uI = (const float*)d_in[6];
  const float* bI = (const float*)d_in[7];
  const float* wC = (const float*)d_in[8];
  const float* uC = (const float*)d_in[9];
  const float* bC = (const float*)d_in[10];
  const float* wO = (const float*)d_in[11];
  const float* uO = (const float*)d_in[12];
  const float* bO = (const float*)d_in[13];
  const float* dw = (const float*)d_in[14];
  const float* db = (const float*)d_in[15];
  float* out = (float*)d_out;

  char* ws = (char*)d_ws;
  size_t off = 0;
  float* XU = (float*)(ws + off); off += (size_t)SEQ * BATCH * 1024 * 4;   // 8 MB
  u32* h0w = (u32*)(ws + off); off += (size_t)SEQ * BATCH * HID * 2;       // bf16 h0
  u32* h1w = (u32*)(ws + off); off += (size_t)SEQ * BATCH * HID * 2;       // bf16 h1
  u32* flg = (u32*)(ws + off); off += (size_t)SEQ * 8 * 4;

  // zero (flags, replay-safe) -> xu (XU with L0 bias folded) ->
  // mega: LSTM blocks 0..7 + 6304 decoder blocks (mb-major) consuming h1 as produced.
  zero_kernel<<<1, 256, 0, stream>>>(flg);
  xu_kernel<<<dim3(128, 4), 256, 0, stream>>>(tokp, embp, uF, uI, uC, uO,
                                              bF, bI, bC, bO, XU);
  mega_kernel<<<8 + DECBLKS, 512, 0, stream>>>(wF, wI, wC, wO, uF, uI, uC, uO,
                                               bF, bI, bC, bO, XU, h0w, h1w, flg,
                                               dw, db, out);
}